// Round 9
// baseline (244.003 us; speedup 1.0000x reference)
//
#include <hip/hip_runtime.h>

#define N_NEUR 512
#define B_SZ   16
#define T_STEPS 32
#define NIN    32
#define NOUT   16
#define CAPC   84   // chem nnz/row cap (mean 48.6, sd 6.63)
#define CAPG   52   // gj nnz/row cap   (mean 25.6, sd 4.93)
#define MCP2   42   // packed col words per thread (full row now)
#define MGP2   26
#define LOG2E  1.4426950408889634f

__device__ __forceinline__ float rcp_fast(float x) {
#if __has_builtin(__builtin_amdgcn_rcpf)
    return __builtin_amdgcn_rcpf(x);
#else
    return 1.0f / x;
#endif
}
__device__ __forceinline__ float exp2_fast(float x) {
#if __has_builtin(__builtin_amdgcn_exp2f)
    return __builtin_amdgcn_exp2f(x);
#else
    return exp2f(x);
#endif
}

// prep1: per row, softplus + mask + ballot-compact into dense per-row tmp CSR.
__global__ __launch_bounds__(64) void prep1_kernel(
    const float* __restrict__ W,
    const float* __restrict__ mex,
    const float* __restrict__ min_,
    const float* __restrict__ mgj,
    int* __restrict__ key_arr, int* __restrict__ ccA, int* __restrict__ cgA,
    int2* __restrict__ tmpC, int2* __restrict__ tmpG)
{
    const int row  = blockIdx.x;
    const int lane = threadIdx.x;
    const unsigned long long below = (1ull << lane) - 1ull;
    int bc = 0, bg = 0;
    for (int c0 = 0; c0 < N_NEUR; c0 += 64) {
        const int col = c0 + lane;
        const int off = row * N_NEUR + col;
        const float w  = W[off];
        const float sp = fmaxf(w, 0.0f) + log1pf(__expf(-fabsf(w)));  // softplus
        const float dm = mex[off] - min_[off];                         // in {-1,0,1}
        bool a = (dm != 0.0f);
        unsigned long long m = __ballot(a);
        int idx = bc + __popcll(m & below);
        if (a && idx < CAPC)
            tmpC[row * CAPC + idx] = make_int2(col, __float_as_int(sp * dm));
        bc += __popcll(m);

        const float g = mgj[off];
        bool ag = (g != 0.0f);
        m = __ballot(ag);
        idx = bg + __popcll(m & below);
        if (ag && idx < CAPG)
            tmpG[row * CAPG + idx] = make_int2(col, __float_as_int(sp * g));
        bg += __popcll(m);
    }
    if (lane == 0) {
        int cc = min(bc, CAPC), cg = min(bg, CAPG);
        ccA[row] = cc; cgA[row] = cg; key_arr[row] = cc + cg;
    }
}

// prep2: per row, rank by nnz (asc); FULL-ROW lists (no h-split -- recur is
// now 1 thread per neuron); bank-stagger rank-sort the whole list; emit
// transposed layout wT[(wv*CAP + k)*64 + myL] with wv = rank>>6,
// myL = rank&63, plus packed byte-offset col pairs.
__global__ __launch_bounds__(64) void prep2_kernel(
    const int* __restrict__ key_arr, const int* __restrict__ ccA, const int* __restrict__ cgA,
    const int2* __restrict__ tmpC, const int2* __restrict__ tmpG,
    int* __restrict__ order,
    float* __restrict__ wCt, unsigned* __restrict__ cpCt,
    float* __restrict__ wGt, unsigned* __restrict__ cpGt)
{
    __shared__ int   cS[CAPC];  __shared__ float wS[CAPC];
    __shared__ int   cSg[CAPG]; __shared__ float wSg[CAPG];
    __shared__ int   keyS[CAPC];
    __shared__ int   scol[CAPC]; __shared__ float sw[CAPC];
    const int d    = blockIdx.x;
    const int lane = threadIdx.x;
    const int kd   = key_arr[d];
    int r = 0;
    for (int j = lane; j < N_NEUR; j += 64) {
        int kj = key_arr[j];
        r += (kj < kd) || (kj == kd && j < d);
    }
    #pragma unroll
    for (int i = 1; i < 64; i <<= 1) r += __shfl_xor(r, i);
    if (lane == 0) order[r] = d;

    const int wv  = r >> 6;           // recur tid = r -> wave r>>6
    const int myL = r & 63;
    const int cc = ccA[d], cg = cgA[d];

    for (int k = lane; k < CAPC; k += 64) {
        int2 e = (k < cc) ? tmpC[d * CAPC + k] : make_int2(0, 0);
        cS[k] = e.x; wS[k] = __int_as_float(e.y);
    }
    for (int k = lane; k < CAPG; k += 64) {
        int2 e = (k < cg) ? tmpG[d * CAPG + k] : make_int2(0, 0);
        cSg[k] = e.x; wSg[k] = __int_as_float(e.y);
    }
    __syncthreads();

    #pragma unroll
    for (int task = 0; task < 2; ++task) {   // {chem, gj}
        const int isG = task;
        const int m   = isG ? cg : cc;       // full-row entry count
        const int CAP = isG ? CAPG : CAPC;
        const int MP  = isG ? MGP2 : MCP2;

        for (int e = lane; e < m; e += 64) {
            int col = isG ? cSg[e] : cS[e];
            keyS[e] = ((col & 31) - myL) & 31;
        }
        __syncthreads();
        for (int e = lane; e < m; e += 64) { // stable rank sort by key
            int key = keyS[e];
            int rk = 0;
            for (int j = 0; j < m; ++j) {
                int kj = keyS[j];
                rk += (kj < key) || (kj == key && j < e);
            }
            scol[rk] = isG ? cSg[e] : cS[e];
            sw[rk]   = isG ? wSg[e] : wS[e];
        }
        __syncthreads();
        float*    wT = isG ? wGt  : wCt;
        unsigned* cT = isG ? cpGt : cpCt;
        for (int k = lane; k < CAP; k += 64)
            wT[(wv * CAP + k) * 64 + myL] = (k < m) ? sw[k] : 0.0f;
        if (lane < MP) {
            unsigned c0 = (2 * lane     < m) ? ((unsigned)scol[2 * lane]     << 2) : 0u;
            unsigned c1 = (2 * lane + 1 < m) ? ((unsigned)scol[2 * lane + 1] << 2) : 0u;
            cT[(wv * MP + lane) * 64 + myL] = c0 | (c1 << 16);
        }
        __syncthreads();                     // scratch reused next task
    }
}

// Gathers read Ob[P] with P COMPILE-TIME: the LDS base folds into the
// ds_read immediate -- per gather: unpack + ds_read + fma, NO base v_add.
#define CHEM_K(P, k, A) {                                                   \
    unsigned pk = cpC[(k) >> 1];                                            \
    unsigned off = ((k) & 1) ? (pk >> 16) : (pk & 0xffffu);                 \
    A = fmaf(wC[k], *(const float*)((const char*)&Ob[P][0] + off), A); }

#define CHEM_C4(P, a) { CHEM_K(P, a, accA) CHEM_K(P, (a)+1, accB) CHEM_K(P, (a)+2, accA) CHEM_K(P, (a)+3, accB) }

#define GJ_K(P, k, A) {                                                     \
    unsigned pk = cpG[(k) >> 1];                                            \
    unsigned off = ((k) & 1) ? (pk >> 16) : (pk & 0xffffu);                 \
    float Os = *(const float*)((const char*)&Ob[P][0] + off);               \
    float f = fmaf(20.0f * LOG2E, Os, cE);                                  \
    float tnh = 1.0f - 2.0f * rcp_fast(1.0f + exp2_fast(f));                \
    A = fmaf(wG[k] * Os, tnh, A); }

#define GJ_C4(P, a) { GJ_K(P, a, accA) GJ_K(P, (a)+1, accB) GJ_K(P, (a)+2, accA) GJ_K(P, (a)+3, accB) }

// One full time-step; chem/gj chunks interleaved (r6's proven pipe-balance).
#define STEP(t, P, Q) {                                                       \
    float ob_next = (injD && ((t) + 1 < T_STEPS)) ? obs_b[((t) + 1) * NIN + d] : 0.0f; \
    float accA = 0.0f, accB = 0.0f;                                           \
    const float cE = -20.0f * LOG2E * E_d;                                    \
    CHEM_C4(P, 0)                                                             \
    GJ_C4(P, 0)                                                               \
    if ( 4 < mCw) CHEM_C4(P, 4)                                               \
    if ( 4 < mGw) GJ_C4(P, 4)                                                 \
    if ( 8 < mCw) CHEM_C4(P, 8)                                               \
    if ( 8 < mGw) GJ_C4(P, 8)                                                 \
    if (12 < mCw) CHEM_C4(P, 12)                                              \
    if (12 < mGw) GJ_C4(P, 12)                                                \
    if (16 < mCw) CHEM_C4(P, 16)                                              \
    if (16 < mGw) GJ_C4(P, 16)                                                \
    if (20 < mCw) CHEM_C4(P, 20)                                              \
    if (20 < mGw) GJ_C4(P, 20)                                                \
    if (24 < mCw) CHEM_C4(P, 24)                                              \
    if (24 < mGw) GJ_C4(P, 24)                                                \
    if (28 < mCw) CHEM_C4(P, 28)                                              \
    if (28 < mGw) GJ_C4(P, 28)                                                \
    if (32 < mCw) CHEM_C4(P, 32)                                              \
    if (32 < mGw) GJ_C4(P, 32)                                                \
    if (36 < mCw) CHEM_C4(P, 36)                                              \
    if (36 < mGw) GJ_C4(P, 36)                                                \
    if (40 < mCw) CHEM_C4(P, 40)                                              \
    if (40 < mGw) GJ_C4(P, 40)                                                \
    if (44 < mCw) CHEM_C4(P, 44)                                              \
    if (44 < mGw) GJ_C4(P, 44)                                                \
    if (48 < mCw) CHEM_C4(P, 48)                                              \
    if (48 < mGw) GJ_C4(P, 48)                                                \
    if (52 < mCw) CHEM_C4(P, 52)                                              \
    if (56 < mCw) CHEM_C4(P, 56)                                              \
    if (60 < mCw) CHEM_C4(P, 60)                                              \
    if (64 < mCw) CHEM_C4(P, 64)                                              \
    if (68 < mCw) CHEM_C4(P, 68)                                              \
    if (72 < mCw) CHEM_C4(P, 72)                                              \
    if (76 < mCw) CHEM_C4(P, 76)                                              \
    if (80 < mCw) CHEM_C4(P, 80)                                              \
    float acc = accA + accB;                                                  \
    float curr = fminf(fmaxf(E_d + acc, -10.0f), 10.0f);                      \
    float z = curr - thr_d;                                                   \
    float O_new = (z >= 0.0f) ? z : 0.01f * z;                                \
    Ob[Q][d] = injD ? ob_next : O_new;          /* early LDS write */         \
    float fg = rcp_fast(1.0f + exp2_fast(-10.0f * LOG2E * z));                \
    float dg = rcp_fast(1.0f + exp2_fast(-5.0f * LOG2E * (fabsf(E_d - curr) - 0.01f))); \
    float E_nf  = dg * curr + (1.0f - dg) * (E_d - dec_d);                    \
    float E_new = fg * O_new + (1.0f - fg) * E_nf;                            \
    if (wr) outp[(t) * NOUT] = E_new;                                         \
    E_d = injD ? ob_next : E_new;                                             \
    __syncthreads();                                                          \
}

// main: one block per batch, 512 threads = 1 per neuron (sorted by nnz).
// 8 waves = 2 waves/EU mandatory -> 256-reg/wave cap (the 1024-thread shape
// forced 4/EU -> 128 cap, which is why every unroll spilled). Full lists in
// registers (~204 words) + x2 t-unroll with compile-time ping-pong bases:
// per gather = unpack + ds_read + fma. No pair_swap, E in register.
__global__ __launch_bounds__(512, 2) void recur_kernel(
    const float* __restrict__ obs,
    const float* __restrict__ thr,
    const float* __restrict__ dec,
    const int* __restrict__ order, const int* __restrict__ ccA, const int* __restrict__ cgA,
    const float* __restrict__ wCt, const unsigned* __restrict__ cpCt,
    const float* __restrict__ wGt, const unsigned* __restrict__ cpGt,
    float* __restrict__ out)
{
    __shared__ float Ob[2][N_NEUR];

    const int b    = blockIdx.x;
    const int tid  = threadIdx.x;
    const int r    = tid;                 // rank
    const int wv   = tid >> 6;
    const int lane = tid & 63;

    const int d = order[r];
    const int cc = ccA[d];
    const int cg = cgA[d];
    const float thr_d = thr[d];
    const float dec_d = dec[d];

    int ccw = cc, cgw = cg;
    #pragma unroll
    for (int i = 1; i < 64; i <<= 1) {
        ccw = max(ccw, __shfl_xor(ccw, i));
        cgw = max(cgw, __shfl_xor(cgw, i));
    }
    const int mCw = __builtin_amdgcn_readfirstlane(ccw);   // full-row trips
    const int mGw = __builtin_amdgcn_readfirstlane(cgw);

    // register-resident full-row lists (zero-padded; pad cols 0 -> broadcast)
    float wC[CAPC]; unsigned cpC[MCP2];
    float wG[CAPG]; unsigned cpG[MGP2];
    #pragma unroll
    for (int k = 0; k < CAPC; ++k) wC[k]  = wCt[(wv * CAPC + k) * 64 + lane];
    #pragma unroll
    for (int k = 0; k < MCP2; ++k) cpC[k] = cpCt[(wv * MCP2 + k) * 64 + lane];
    #pragma unroll
    for (int k = 0; k < CAPG; ++k) wG[k]  = wGt[(wv * CAPG + k) * 64 + lane];
    #pragma unroll
    for (int k = 0; k < MGP2; ++k) cpG[k] = cpGt[(wv * MGP2 + k) * 64 + lane];

    const bool injD = (d < NIN);
    const bool wr   = (d >= NIN) && (d < NIN + NOUT);
    float* outp = out + (size_t)b * T_STEPS * NOUT + (d - NIN);
    const float* obs_b = obs + b * (T_STEPS * NIN);

    // state 0 = zeros + obs_0; E lives in a register
    float E_d = injD ? obs_b[d] : 0.0f;
    Ob[0][d] = E_d;
    __syncthreads();

    for (int t = 0; t < T_STEPS; t += 2) {
        STEP(t,     0, 1)
        STEP(t + 1, 1, 0)
    }
}

extern "C" void kernel_launch(void* const* d_in, const int* in_sizes, int n_in,
                              void* d_out, int out_size, void* d_ws, size_t ws_size,
                              hipStream_t stream)
{
    const float* obs  = (const float*)d_in[0];
    const float* W    = (const float*)d_in[1];
    const float* thr  = (const float*)d_in[2];
    const float* dec  = (const float*)d_in[3];
    const float* mex  = (const float*)d_in[4];
    const float* min_ = (const float*)d_in[5];
    const float* mgj  = (const float*)d_in[6];
    float* out = (float*)d_out;

    char* ws = (char*)d_ws;
    int*   key_arr = (int*)(ws);
    int*   ccA     = (int*)(ws + 2048);
    int*   cgA     = (int*)(ws + 4096);
    int*   order   = (int*)(ws + 6144);
    int2*  tmpC    = (int2*)(ws + 8192);                   // 512*84*8 = 344064
    int2*  tmpG    = (int2*)(ws + 8192 + 344064);          // 512*52*8 = 212992
    float* wCt     = (float*)(ws + 565248);                // 8*84*64*4 = 172032
    unsigned* cpCt = (unsigned*)(ws + 737280);             // 8*42*64*4 =  86016
    float* wGt     = (float*)(ws + 823296);                // 8*52*64*4 = 106496
    unsigned* cpGt = (unsigned*)(ws + 929792);             // 8*26*64*4 =  53248
    // total ws use: ~983 KB (identical byte layout to r6)

    prep1_kernel<<<N_NEUR, 64, 0, stream>>>(W, mex, min_, mgj,
                                            key_arr, ccA, cgA, tmpC, tmpG);
    prep2_kernel<<<N_NEUR, 64, 0, stream>>>(key_arr, ccA, cgA, tmpC, tmpG,
                                            order, wCt, cpCt, wGt, cpGt);
    recur_kernel<<<B_SZ, 512, 0, stream>>>(obs, thr, dec,
                                           order, ccA, cgA,
                                           wCt, cpCt, wGt, cpGt, out);
}

// Round 11
// 174.279 us; speedup vs baseline: 1.4001x; 1.4001x over previous
//
#include <hip/hip_runtime.h>

#define N_NEUR 512
#define B_SZ   16
#define T_STEPS 32
#define NIN    32
#define NOUT   16
#define CAPC   84   // chem nnz/row cap (mean 48.6, sd 6.63)
#define CAPG   52   // gj nnz/row cap   (mean 25.6, sd 4.93)
#define MC     42   // per-thread chem entries (h splits CSR evens/odds)
#define MG     26
#define MCP    21   // packed col words per thread
#define MGP    13
#define LOG2E  1.4426950408889634f

__device__ __forceinline__ float rcp_fast(float x) {
#if __has_builtin(__builtin_amdgcn_rcpf)
    return __builtin_amdgcn_rcpf(x);
#else
    return 1.0f / x;
#endif
}
__device__ __forceinline__ float exp2_fast(float x) {
#if __has_builtin(__builtin_amdgcn_exp2f)
    return __builtin_amdgcn_exp2f(x);
#else
    return exp2f(x);
#endif
}
// cross-pair sum WITHOUT the DS pipe: DPP quad_perm [1,0,3,2]
__device__ __forceinline__ float pair_swap(float x) {
#if __has_builtin(__builtin_amdgcn_mov_dpp)
    return __int_as_float(__builtin_amdgcn_mov_dpp(__float_as_int(x), 0xB1, 0xF, 0xF, true));
#else
    return __shfl_xor(x, 1);
#endif
}

// prep1: per row, softplus + mask + ballot-compact into dense per-row tmp CSR.
__global__ __launch_bounds__(64) void prep1_kernel(
    const float* __restrict__ W,
    const float* __restrict__ mex,
    const float* __restrict__ min_,
    const float* __restrict__ mgj,
    int* __restrict__ key_arr, int* __restrict__ ccA, int* __restrict__ cgA,
    int2* __restrict__ tmpC, int2* __restrict__ tmpG)
{
    const int row  = blockIdx.x;
    const int lane = threadIdx.x;
    const unsigned long long below = (1ull << lane) - 1ull;
    int bc = 0, bg = 0;
    for (int c0 = 0; c0 < N_NEUR; c0 += 64) {
        const int col = c0 + lane;
        const int off = row * N_NEUR + col;
        const float w  = W[off];
        const float sp = fmaxf(w, 0.0f) + log1pf(__expf(-fabsf(w)));  // softplus
        const float dm = mex[off] - min_[off];                         // in {-1,0,1}
        bool a = (dm != 0.0f);
        unsigned long long m = __ballot(a);
        int idx = bc + __popcll(m & below);
        if (a && idx < CAPC)
            tmpC[row * CAPC + idx] = make_int2(col, __float_as_int(sp * dm));
        bc += __popcll(m);

        const float g = mgj[off];
        bool ag = (g != 0.0f);
        m = __ballot(ag);
        idx = bg + __popcll(m & below);
        if (ag && idx < CAPG)
            tmpG[row * CAPG + idx] = make_int2(col, __float_as_int(sp * g));
        bg += __popcll(m);
    }
    if (lane == 0) {
        int cc = min(bc, CAPC), cg = min(bg, CAPG);
        ccA[row] = cc; cgA[row] = cg; key_arr[row] = cc + cg;
    }
}

// prep2: per row, rank by nnz (asc); split each row's CSR into evens/odds
// (h); bank-stagger rank-sort each half-list; emit transposed layout
// wT[(wv*M + k)*64 + lane], packed byte-scaled col pairs in cT.
// (r0/r6 layout exactly.)
__global__ __launch_bounds__(64) void prep2_kernel(
    const int* __restrict__ key_arr, const int* __restrict__ ccA, const int* __restrict__ cgA,
    const int2* __restrict__ tmpC, const int2* __restrict__ tmpG,
    int* __restrict__ order,
    float* __restrict__ wCt, unsigned* __restrict__ cpCt,
    float* __restrict__ wGt, unsigned* __restrict__ cpGt)
{
    __shared__ int   cS[CAPC];  __shared__ float wS[CAPC];
    __shared__ int   cSg[CAPG]; __shared__ float wSg[CAPG];
    __shared__ int   keyS[MC];
    __shared__ int   scol[MC];  __shared__ float sw[MC];
    const int d    = blockIdx.x;
    const int lane = threadIdx.x;
    const int kd   = key_arr[d];
    int r = 0;
    for (int j = lane; j < N_NEUR; j += 64) {
        int kj = key_arr[j];
        r += (kj < kd) || (kj == kd && j < d);
    }
    #pragma unroll
    for (int i = 1; i < 64; i <<= 1) r += __shfl_xor(r, i);
    if (lane == 0) order[r] = d;

    const int wv = r >> 5;            // main tid = 2r+h -> wv = r>>5
    const int Lb = 2 * (r & 31);
    const int cc = ccA[d], cg = cgA[d];

    for (int k = lane; k < CAPC; k += 64) {
        int2 e = (k < cc) ? tmpC[d * CAPC + k] : make_int2(0, 0);
        cS[k] = e.x; wS[k] = __int_as_float(e.y);
    }
    for (int k = lane; k < CAPG; k += 64) {
        int2 e = (k < cg) ? tmpG[d * CAPG + k] : make_int2(0, 0);
        cSg[k] = e.x; wSg[k] = __int_as_float(e.y);
    }
    __syncthreads();

    #pragma unroll
    for (int task = 0; task < 4; ++task) {   // {chem,gj} x {h0,h1}
        const int isG = task >> 1, h = task & 1;
        const int cnt = isG ? cg : cc;
        const int m   = (cnt + 1 - h) >> 1;  // entries in this half-list
        const int M   = isG ? MG : MC;
        const int MP  = isG ? MGP : MCP;
        const int myL = Lb + h;              // owner lane in the main kernel

        int col = 0; float w = 0.0f; int key = 0;
        if (lane < m) {                      // lane k owns CSR entry 2k+h
            col = isG ? cSg[2 * lane + h] : cS[2 * lane + h];
            w   = isG ? wSg[2 * lane + h] : wS[2 * lane + h];
            key = ((col & 31) - myL) & 31;
            keyS[lane] = key;
        }
        __syncthreads();
        if (lane < m) {
            int rk = 0;
            for (int j = 0; j < m; ++j) {
                int kj = keyS[j];
                rk += (kj < key) || (kj == key && j < lane);
            }
            scol[rk] = col; sw[rk] = w;
        }
        __syncthreads();
        float*    wT = isG ? wGt  : wCt;
        unsigned* cT = isG ? cpGt : cpCt;
        if (lane < M)
            wT[(wv * M + lane) * 64 + myL] = (lane < m) ? sw[lane] : 0.0f;
        if (lane < MP) {
            unsigned c0 = (2 * lane     < m) ? ((unsigned)scol[2 * lane]     << 2) : 0u;
            unsigned c1 = (2 * lane + 1 < m) ? ((unsigned)scol[2 * lane + 1] << 2) : 0u;
            cT[(wv * MP + lane) * 64 + myL] = c0 | (c1 << 16);
        }
        __syncthreads();                     // scol/keyS reused next task
    }
}

#define CHEM_K(k, A) {                                                      \
    unsigned pk = cpC[(k) >> 1];                                            \
    unsigned off = ((k) & 1) ? (pk >> 16) : (pk & 0xffffu);                 \
    A = fmaf(wC[k], *(const float*)((const char*)ObP + off), A); }

#define CHEM_C4(a) { CHEM_K(a, accA) CHEM_K((a)+1, accB) CHEM_K((a)+2, accA) CHEM_K((a)+3, accB) }

#define GJ_K(k, A) {                                                        \
    unsigned pk = cpG[(k) >> 1];                                            \
    unsigned off = ((k) & 1) ? (pk >> 16) : (pk & 0xffffu);                 \
    float Os = *(const float*)((const char*)ObP + off);                     \
    float f = fmaf(20.0f * LOG2E, Os, cE);                                  \
    float tnh = 1.0f - 2.0f * rcp_fast(1.0f + exp2_fast(f));                \
    A = fmaf(wG[k] * Os, tnh, A); }

#define GJ_C4(a) { GJ_K(a, accA) GJ_K((a)+1, accB) GJ_K((a)+2, accA) GJ_K((a)+3, accB) }

// main: one block per batch, 1024 threads = 2 per neuron (sorted by nnz).
// EXACT r6 body (94.8us: chem/gj interleave, E in register, runtime
// ping-pong, one barrier/step -- the register-feasible optimum; r8/r9
// mapped the 128-reg wall from both sides). Two zero-register additions:
//  1. outputs staged in LDS, dumped once after the loop -- removes the
//     per-step global store whose ack the pre-barrier vmcnt(0) drains.
//  2. Ob[q] write issued right after O_new (before fg/dg trans chains):
//     the lgkmcnt the barrier needs starts draining earlier.
__global__ __launch_bounds__(1024, 1) void recur_kernel(
    const float* __restrict__ obs,
    const float* __restrict__ thr,
    const float* __restrict__ dec,
    const int* __restrict__ order, const int* __restrict__ ccA, const int* __restrict__ cgA,
    const float* __restrict__ wCt, const unsigned* __restrict__ cpCt,
    const float* __restrict__ wGt, const unsigned* __restrict__ cpGt,
    float* __restrict__ out)
{
    __shared__ float Ob[2][N_NEUR];
    __shared__ float outS[T_STEPS * NOUT];

    const int b    = blockIdx.x;
    const int tid  = threadIdx.x;
    const int h    = tid & 1;
    const int r    = tid >> 1;            // rank
    const int wv   = tid >> 6;
    const int lane = tid & 63;

    const int d = order[r];
    const int cc = ccA[d];
    const int cg = cgA[d];
    const float thr_d = thr[d];
    const float dec_d = dec[d];

    int ccw = cc, cgw = cg;
    #pragma unroll
    for (int i = 1; i < 64; i <<= 1) {
        ccw = max(ccw, __shfl_xor(ccw, i));
        cgw = max(cgw, __shfl_xor(cgw, i));
    }
    const int mCw = __builtin_amdgcn_readfirstlane((ccw + 1) >> 1);
    const int mGw = __builtin_amdgcn_readfirstlane((cgw + 1) >> 1);

    // register-resident lists (zero-padded; padding cols are 0 -> broadcast)
    float wC[MC]; unsigned cpC[MCP];
    float wG[MG]; unsigned cpG[MGP];
    #pragma unroll
    for (int k = 0; k < MC; ++k)  wC[k]  = wCt[(wv * MC + k) * 64 + lane];
    #pragma unroll
    for (int k = 0; k < MCP; ++k) cpC[k] = cpCt[(wv * MCP + k) * 64 + lane];
    #pragma unroll
    for (int k = 0; k < MG; ++k)  wG[k]  = wGt[(wv * MG + k) * 64 + lane];
    #pragma unroll
    for (int k = 0; k < MGP; ++k) cpG[k] = cpGt[(wv * MGP + k) * 64 + lane];

    const bool injD = (d < NIN);          // neuron-level (both halves)
    const bool wr   = (h == 0) && (d >= NIN) && (d < NIN + NOUT);
    const int  oidx = d - NIN;
    const float* obs_b = obs + b * (T_STEPS * NIN);

    // state 0 = zeros + obs_0; E lives in a register (both halves carry it)
    float E_d = injD ? obs_b[d] : 0.0f;
    if (h == 0) Ob[0][d] = E_d;
    int p = 0;
    __syncthreads();

    for (int t = 0; t < T_STEPS; ++t) {
        // prefetch obs_{t+1} (both halves: it feeds the E register carry)
        float ob_next = (injD && (t + 1 < T_STEPS)) ? obs_b[(t + 1) * NIN + d] : 0.0f;

        const float* ObP = Ob[p];
        float accA = 0.0f, accB = 0.0f;
        const float cE = -20.0f * LOG2E * E_d;
        // chem (DS-heavy) and gj (VALU/trans-heavy) chunks interleaved
        CHEM_C4(0)
        GJ_C4(0)
        if ( 4 < mCw) CHEM_C4(4)
        if ( 4 < mGw) GJ_C4(4)
        if ( 8 < mCw) CHEM_C4(8)
        if ( 8 < mGw) GJ_C4(8)
        if (12 < mCw) CHEM_C4(12)
        if (12 < mGw) GJ_C4(12)
        if (16 < mCw) CHEM_C4(16)
        if (16 < mGw) GJ_C4(16)
        if (20 < mCw) CHEM_C4(20)
        if (20 < mGw) GJ_C4(20)
        if (24 < mCw) CHEM_C4(24)
        if (24 < mGw) { GJ_K(24, accA) GJ_K(25, accB) }
        if (28 < mCw) CHEM_C4(28)
        if (32 < mCw) CHEM_C4(32)
        if (36 < mCw) CHEM_C4(36)
        if (40 < mCw) { CHEM_K(40, accA) CHEM_K(41, accB) }

        float acc = accA + accB;
        acc += pair_swap(acc);

        // epilogue (both halves compute the same E_new; h==0 writes LDS)
        float curr = fminf(fmaxf(E_d + acc, -10.0f), 10.0f);
        float z = curr - thr_d;
        float O_new = (z >= 0.0f) ? z : 0.01f * z;
        const int q = p ^ 1;
        if (h == 0) Ob[q][d] = injD ? ob_next : O_new;   // EARLY LDS write
        float fg = rcp_fast(1.0f + exp2_fast(-10.0f * LOG2E * z));
        float dg = rcp_fast(1.0f + exp2_fast(-5.0f * LOG2E * (fabsf(E_d - curr) - 0.01f)));
        float E_nf  = dg * curr + (1.0f - dg) * (E_d - dec_d);
        float E_new = fg * O_new + (1.0f - fg) * E_nf;

        if (wr) outS[t * NOUT + oidx] = E_new;           // LDS, not global
        E_d = injD ? ob_next : E_new;     // register carry replaces Eb
        __syncthreads();
        p = q;
    }

    // one coalesced output dump per block (the only global store)
    if (tid < T_STEPS * NOUT)
        out[(size_t)b * (T_STEPS * NOUT) + tid] = outS[tid];
}

extern "C" void kernel_launch(void* const* d_in, const int* in_sizes, int n_in,
                              void* d_out, int out_size, void* d_ws, size_t ws_size,
                              hipStream_t stream)
{
    const float* obs  = (const float*)d_in[0];
    const float* W    = (const float*)d_in[1];
    const float* thr  = (const float*)d_in[2];
    const float* dec  = (const float*)d_in[3];
    const float* mex  = (const float*)d_in[4];
    const float* min_ = (const float*)d_in[5];
    const float* mgj  = (const float*)d_in[6];
    float* out = (float*)d_out;

    char* ws = (char*)d_ws;
    int*   key_arr = (int*)(ws);
    int*   ccA     = (int*)(ws + 2048);
    int*   cgA     = (int*)(ws + 4096);
    int*   order   = (int*)(ws + 6144);
    int2*  tmpC    = (int2*)(ws + 8192);                   // 512*84*8 = 344064
    int2*  tmpG    = (int2*)(ws + 8192 + 344064);          // 512*52*8 = 212992
    float* wCt     = (float*)(ws + 565248);                // 16*42*64*4 = 172032
    unsigned* cpCt = (unsigned*)(ws + 737280);             // 16*21*64*4 =  86016
    float* wGt     = (float*)(ws + 823296);                // 16*26*64*4 = 106496
    unsigned* cpGt = (unsigned*)(ws + 929792);             // 16*13*64*4 =  53248
    // total ws use: ~983 KB

    prep1_kernel<<<N_NEUR, 64, 0, stream>>>(W, mex, min_, mgj,
                                            key_arr, ccA, cgA, tmpC, tmpG);
    prep2_kernel<<<N_NEUR, 64, 0, stream>>>(key_arr, ccA, cgA, tmpC, tmpG,
                                            order, wCt, cpCt, wGt, cpGt);
    recur_kernel<<<B_SZ, 1024, 0, stream>>>(obs, thr, dec,
                                            order, ccA, cgA,
                                            wCt, cpCt, wGt, cpGt, out);
}